// Round 2
// baseline (233.037 us; speedup 1.0000x reference)
//
#include <hip/hip_runtime.h>

// OTAM cumulative distance on MI355X.
// Per (q,s) pair: 16x16 tile D = 1 - sim. Two banded soft-min DPs
// (forward and transposed), each result = cum[15][17]; out = -0.5*(F+T).
//
// Both DPs advance one ORIGINAL row at a time:
//   - forward DP: row-recurrence, state prev[18]
//   - transposed DP: column-sweep of the transposed matrix (column jj = l+1
//     of d^T IS original row l), state S[16]
// so the tile is streamed from global exactly once, 64B (one cache line)
// per row per thread.

#define KSC 14.426950408889634f   // (1/lbda)*log2(e) = 10*1.4426950408889634
#define CL2 0.06931471805599453f  // lbda*ln(2)

#if __has_builtin(__builtin_amdgcn_exp2f)
#define EXP2(x) __builtin_amdgcn_exp2f(x)
#else
#define EXP2(x) exp2f(x)
#endif
#if __has_builtin(__builtin_amdgcn_logf)
#define LOG2(x) __builtin_amdgcn_logf(x)
#else
#define LOG2(x) log2f(x)
#endif

static __device__ __forceinline__ float sm2(float a, float b) {
    float mn = fminf(a, b), mx = fmaxf(a, b);
    float e  = EXP2((mn - mx) * KSC);
    return mn - CL2 * LOG2(1.0f + e);
}

static __device__ __forceinline__ float sm3(float a, float b, float c) {
    float mn = fminf(fminf(a, b), c);
    float s  = EXP2((mn - a) * KSC)
             + EXP2((mn - b) * KSC)
             + EXP2((mn - c) * KSC);
    return mn - CL2 * LOG2(s);
}

// Forward DP, one row l>=1: cum[l][m] = d[l][m] + softmin(cum[l-1][m-1],
// cum[l][m-1], [cum[l-1][m] if m==1||m==17]).  In-place on prev[18].
static __device__ __forceinline__ void fwd_row(float (&prev)[18], const float (&r)[16]) {
    float a_old = prev[0];   // cum[l-1][m-1]; prev[0] == 0
    float cur   = 0.0f;      // cum[l][0] == 0
#pragma unroll
    for (int m = 1; m <= 17; ++m) {
        float t  = prev[m];  // cum[l-1][m] (old)
        float v  = (m <= 16) ? r[m - 1] : 0.0f;          // padded col 17 -> 0
        float sm = (m == 1 || m == 17) ? sm3(a_old, cur, t) : sm2(a_old, cur);
        cur     = v + sm;
        prev[m] = cur;
        a_old   = t;
    }
}

// Transposed DP, advance one column jj (data = original row l = jj-1).
// cum2[0][jj] = cum2[0][jj-1] + r[0]  (prefix row of the transposed DP)
// cum2[i][jj] = r[i] + softmin(cum2[i-1][jj-1], cum2[i][jj-1],
//                              [cum2[i-1][jj] if jj==1||jj==17])
template <bool BND>
static __device__ __forceinline__ void dp2_col(float (&S)[16], const float (&r)[16]) {
    float po  = S[0];        // cum2[i-1][jj-1]
    float cur = S[0] + r[0];
    S[0] = cur;
#pragma unroll
    for (int i = 1; i < 16; ++i) {
        float t  = S[i];     // cum2[i][jj-1] (old)
        float sm = BND ? sm3(po, t, cur) : sm2(po, t);
        cur  = r[i] + sm;
        S[i] = cur;
        po   = t;
    }
}

#define UNPACK(r, b0, b1, b2, b3)                                          \
    r[0]=1.0f-b0.x;  r[1]=1.0f-b0.y;  r[2]=1.0f-b0.z;  r[3]=1.0f-b0.w;     \
    r[4]=1.0f-b1.x;  r[5]=1.0f-b1.y;  r[6]=1.0f-b1.z;  r[7]=1.0f-b1.w;     \
    r[8]=1.0f-b2.x;  r[9]=1.0f-b2.y;  r[10]=1.0f-b2.z; r[11]=1.0f-b2.w;    \
    r[12]=1.0f-b3.x; r[13]=1.0f-b3.y; r[14]=1.0f-b3.z; r[15]=1.0f-b3.w

__global__ __launch_bounds__(64) void otam_kernel(const float* __restrict__ sim,
                                                  float* __restrict__ out,
                                                  int npairs) {
    int p = blockIdx.x * 64 + threadIdx.x;
    if (p >= npairs) return;
    const float4* tp = (const float4*)(sim + (size_t)p * 256);

    float prev[18], S[16], r[16];

    // row 0 + prefetch row 1
    float4 b0 = tp[0], b1 = tp[1], b2 = tp[2], b3 = tp[3];
    float4 c0 = tp[4], c1 = tp[5], c2 = tp[6], c3 = tp[7];

    UNPACK(r, b0, b1, b2, b3);

    // forward DP row 0: prefix sums (padded col 17 adds 0)
    prev[0] = 0.0f;
#pragma unroll
    for (int m = 1; m <= 16; ++m) prev[m] = prev[m - 1] + r[m - 1];
    prev[17] = prev[16];

    // transposed DP column jj=1 (boundary); previous column is all zeros
#pragma unroll
    for (int i = 0; i < 16; ++i) S[i] = 0.0f;
    dp2_col<true>(S, r);

    for (int l = 1; l < 16; ++l) {
        b0 = c0; b1 = c1; b2 = c2; b3 = c3;
        if (l < 15) {  // prefetch next row
            c0 = tp[(l + 1) * 4 + 0];
            c1 = tp[(l + 1) * 4 + 1];
            c2 = tp[(l + 1) * 4 + 2];
            c3 = tp[(l + 1) * 4 + 3];
        }
        UNPACK(r, b0, b1, b2, b3);
        fwd_row(prev, r);
        dp2_col<false>(S, r);   // jj = l+1 in 2..16: not boundary
    }

    // transposed DP final column jj=17 (boundary, padded data = 0)
    float z[16];
#pragma unroll
    for (int i = 0; i < 16; ++i) z[i] = 0.0f;
    dp2_col<true>(S, z);

    out[p] = -0.5f * (prev[17] + S[15]);
}

extern "C" void kernel_launch(void* const* d_in, const int* in_sizes, int n_in,
                              void* d_out, int out_size, void* d_ws, size_t ws_size,
                              hipStream_t stream) {
    const float* sim = (const float*)d_in[0];
    float* out       = (float*)d_out;
    int npairs = in_sizes[0] / 256;            // 400*400 = 160000
    int blocks = (npairs + 63) / 64;           // 2500 single-wave blocks
    otam_kernel<<<blocks, 64, 0, stream>>>(sim, out, npairs);
}